// Round 15
// baseline (367.645 us; speedup 1.0000x reference)
//
#include <hip/hip_runtime.h>
#include <stdint.h>

// ---------- types ----------
typedef __attribute__((ext_vector_type(8))) _Float16 half8;  // MFMA A/B frag (4 VGPR)
typedef __attribute__((ext_vector_type(4))) _Float16 half4;  // 8B store
typedef __attribute__((ext_vector_type(2))) __fp16 fp16x2;   // cvt_pkrtz result type
typedef __attribute__((ext_vector_type(4))) float f32x4;     // MFMA C/D frag

#define AS1 __attribute__((address_space(1)))
#define AS3 __attribute__((address_space(3)))

__device__ inline void gload_lds16(const void* g, void* l) {
  __builtin_amdgcn_global_load_lds((const AS1 void*)g, (AS3 void*)l, 16, 0, 0);
}
__device__ inline f32x4 mfma16h(half8 a, half8 b, f32x4 c) {
  return __builtin_amdgcn_mfma_f32_16x16x32_f16(a, b, c, 0, 0, 0);
}

// ---------- x fp32 -> fp16 hi + fp16 lo*4096 (exact residual split) ----------
__global__ __launch_bounds__(256) void cvt_split(const float4* __restrict__ in,
                                                 half4* __restrict__ xh,
                                                 half4* __restrict__ xl, int nq) {
  int i = blockIdx.x * 256 + threadIdx.x;
  if (i >= nq) return;
  float4 v = in[i];
  float vv[4] = {v.x, v.y, v.z, v.w};
  half4 h, lo;
#pragma unroll
  for (int j = 0; j < 4; ++j) {
    _Float16 hh = (_Float16)vv[j];
    h[j] = hh;
    lo[j] = (_Float16)((vv[j] - (float)hh) * 4096.0f);
  }
  xh[i] = h;
  xl[i] = lo;
}

// ---------- transpose fp32 RxC -> fp16 CxR (+opt lo split, +opt row scale, +z-pair) ----------
__global__ __launch_bounds__(256) void transpose_f16(const float* __restrict__ in,
                                                     const float* __restrict__ in2,
                                                     _Float16* __restrict__ outh,
                                                     _Float16* __restrict__ outl,
                                                     const float* __restrict__ rowamax,
                                                     int R, int C) {
  __shared__ float t[32][33];
  if (blockIdx.z) { in = in2; outh += (size_t)R * C; }
  const int tx = threadIdx.x, ty = threadIdx.y;
  const int r0 = blockIdx.y * 32, c0 = blockIdx.x * 32;
#pragma unroll
  for (int k = 0; k < 4; ++k) {
    const int r = r0 + ty + k * 8;
    float s = 1.0f;
    if (rowamax) s = fmaxf(rowamax[r], 1e-5f) / 7.0f;   // same expr as quant kernel
    t[ty + k * 8][tx] = in[(size_t)r * C + c0 + tx] * s;
  }
  __syncthreads();
#pragma unroll
  for (int k = 0; k < 4; ++k) {
    const int c = c0 + ty + k * 8;
    float v = t[tx][ty + k * 8];
    _Float16 h = (_Float16)v;
    outh[(size_t)c * R + r0 + tx] = h;
    if (outl) outl[(size_t)c * R + r0 + tx] = (_Float16)((v - (float)h) * 4096.0f);
  }
}

// ---------- kv_latent GEMM via fp16 hi/lo 3-term MFMA (fp32-equivalent) ----------
// BM=128 x BN=64 tile (r15 retile: B re-reads halve, traffic 512->384MB). 4 waves,
// wave tile 32x64 (wr=w). Per-element K-chain order unchanged -> bitwise-same kv.
__global__ __launch_bounds__(256) void gemm_kv16(const _Float16* __restrict__ Ah,
                                                 const _Float16* __restrict__ Al,
                                                 const _Float16* __restrict__ Bh,
                                                 const _Float16* __restrict__ Bl,
                                                 const float* __restrict__ bias,
                                                 float* __restrict__ C,
                                                 float* __restrict__ amax,
                                                 int M, int N, int K) {
  __shared__ _Float16 sAh[128 * 64], sAl[128 * 64];   // 16KB each
  __shared__ _Float16 sBh[64 * 64], sBl[64 * 64];     // 8KB each
  const int tid = threadIdx.x;
  const int w = tid >> 6, l = tid & 63, g = l >> 4, c = l & 15;
  int wgid = blockIdx.x + blockIdx.y * gridDim.x;
  const int nwg = gridDim.x * gridDim.y;
  wgid = (wgid & 7) * (nwg >> 3) + (wgid >> 3);
  const int tm0 = (wgid / gridDim.x) * 128, n0 = (wgid % gridDim.x) * 64;

  f32x4 acc[2][4], acc2[2][4];
#pragma unroll
  for (int i = 0; i < 2; ++i)
#pragma unroll
    for (int j = 0; j < 4; ++j) {
      acc[i][j] = f32x4{0.f, 0.f, 0.f, 0.f};
      acc2[i][j] = f32x4{0.f, 0.f, 0.f, 0.f};
    }

  for (int k0 = 0; k0 < K; k0 += 64) {
#pragma unroll
    for (int cc = 0; cc < 4; ++cc) {                 // A hi/lo: 16KB each
      const int off = w * 4096 + cc * 1024 + l * 16;
      const int row = off >> 7, colb = off & 127;
      const char* gA = (const char*)Ah + ((size_t)(tm0 + row) * K + k0) * 2 + colb;
      const char* gL = (const char*)Al + ((size_t)(tm0 + row) * K + k0) * 2 + colb;
      gload_lds16(gA, (char*)sAh + w * 4096 + cc * 1024);
      gload_lds16(gL, (char*)sAl + w * 4096 + cc * 1024);
    }
#pragma unroll
    for (int cc = 0; cc < 2; ++cc) {                 // B hi/lo: 8KB each
      const int off = w * 2048 + cc * 1024 + l * 16;
      const int row = off >> 7, colb = off & 127;
      const char* gB = (const char*)Bh + ((size_t)(n0 + row) * K + k0) * 2 + colb;
      const char* gL = (const char*)Bl + ((size_t)(n0 + row) * K + k0) * 2 + colb;
      gload_lds16(gB, (char*)sBh + w * 2048 + cc * 1024);
      gload_lds16(gL, (char*)sBl + w * 2048 + cc * 1024);
    }
    __syncthreads();
#pragma unroll
    for (int ks = 0; ks < 2; ++ks) {
      half8 ah[2], al[2], bh[4], bl[4];
#pragma unroll
      for (int i = 0; i < 2; ++i) {
        ah[i] = *(const half8*)&sAh[(w * 32 + i * 16 + c) * 64 + ks * 32 + g * 8];
        al[i] = *(const half8*)&sAl[(w * 32 + i * 16 + c) * 64 + ks * 32 + g * 8];
      }
#pragma unroll
      for (int j = 0; j < 4; ++j) {
        bh[j] = *(const half8*)&sBh[(j * 16 + c) * 64 + ks * 32 + g * 8];
        bl[j] = *(const half8*)&sBl[(j * 16 + c) * 64 + ks * 32 + g * 8];
      }
#pragma unroll
      for (int i = 0; i < 2; ++i)
#pragma unroll
        for (int j = 0; j < 4; ++j) {
          acc[i][j] = mfma16h(ah[i], bh[j], acc[i][j]);
          acc2[i][j] = mfma16h(al[i], bh[j], acc2[i][j]);
          acc2[i][j] = mfma16h(ah[i], bl[j], acc2[i][j]);
        }
    }
    __syncthreads();
  }

  float cm[4] = {0.f, 0.f, 0.f, 0.f};
#pragma unroll
  for (int i = 0; i < 2; ++i) {
    const int row0 = tm0 + w * 32 + i * 16 + g * 4;
#pragma unroll
    for (int j = 0; j < 4; ++j) {
      const int col = n0 + j * 16 + c;
      const float bv = bias[col];
#pragma unroll
      for (int r = 0; r < 4; ++r) {
        float v = acc[i][j][r] + acc2[i][j][r] * 2.44140625e-4f + bv;  // 2^-12 exact
        C[(size_t)(row0 + r) * N + col] = v;
        cm[j] = fmaxf(cm[j], fabsf(v));
      }
    }
  }
#pragma unroll
  for (int j = 0; j < 4; ++j) {
    float m = cm[j];
    m = fmaxf(m, __shfl_xor(m, 16, 64));
    m = fmaxf(m, __shfl_xor(m, 32, 64));
    if (g == 0) atomicMax((int*)amax + (n0 + j * 16 + c), __float_as_int(m));
  }
}

// ---------- int4 quant: store INTEGER q (-8..7) as fp16 (exact) ----------
__global__ __launch_bounds__(256) void quant_kernel(const float4* __restrict__ kv,
                                                    const float* __restrict__ amax,
                                                    half4* __restrict__ kvq, int nq) {
  int i = blockIdx.x * 256 + threadIdx.x;
  if (i >= nq) return;
  float4 v = kv[i];
  int r0 = (i * 4) & 511;
  half4 o;
#pragma unroll
  for (int j = 0; j < 4; ++j) {
    float s = fmaxf(amax[r0 + j], 1e-5f) / 7.0f;
    float val = (j == 0) ? v.x : (j == 1) ? v.y : (j == 2) ? v.z : v.w;
    float q = rintf(val / s);                         // round-half-even == jnp.round
    q = fminf(7.f, fmaxf(-8.f, q));
    o[j] = (_Float16)q;                               // small ints exact
  }
  kvq[i] = o;
}

// ---------- fp16 MFMA GEMM: C = A @ BT^T + bias.  A: MxK, BT: NxK ----------
// BM=128 x BN=256 tile (r15 retile: A re-reads halve; q/out 512->384MB, upproj
// 256->192MB). 4 waves, wave tile 64x128 (acc[4][8]). K-chain per element
// unchanged -> bitwise-identical C. MODE 0: f16 row-major (×cscale); MODE 2: fp32;
// MODE 4: fused k/v up-proj (cols<2048 -> K blocked; cols>=2048 -> V blocked).
template <int MODE>
__global__ __launch_bounds__(256) void gemm_bt(const _Float16* __restrict__ A,
                                               const _Float16* __restrict__ BT,
                                               void* __restrict__ Cout,
                                               void* __restrict__ Cout2,
                                               const float* __restrict__ bias,
                                               const float* __restrict__ bias2,
                                               float cscale,
                                               int M, int N, int K) {
  __shared__ _Float16 As[128 * 64];    // 16KB
  __shared__ _Float16 Bs[256 * 64];    // 32KB
  const int tid = threadIdx.x;
  const int w = tid >> 6, l = tid & 63, g = l >> 4, c = l & 15;
  const int wr = w >> 1, wc = w & 1;   // wave tile 64(M) x 128(N)
  int wgid = blockIdx.x + blockIdx.y * gridDim.x;
  const int nwg = gridDim.x * gridDim.y;
  wgid = (wgid & 7) * (nwg >> 3) + (wgid >> 3);
  const int tm0 = (wgid / gridDim.x) * 128, tn0 = (wgid % gridDim.x) * 256;

  f32x4 acc[4][8];
#pragma unroll
  for (int i = 0; i < 4; ++i)
#pragma unroll
    for (int j = 0; j < 8; ++j) acc[i][j] = f32x4{0.f, 0.f, 0.f, 0.f};

  for (int k0 = 0; k0 < K; k0 += 64) {
#pragma unroll
    for (int cc = 0; cc < 4; ++cc) {   // A: 16KB
      const int off = w * 4096 + cc * 1024 + l * 16;
      const int row = off >> 7, colb = off & 127;
      const char* gA = (const char*)A + ((size_t)(tm0 + row) * K + k0) * 2 + colb;
      gload_lds16(gA, (char*)As + w * 4096 + cc * 1024);
    }
#pragma unroll
    for (int cc = 0; cc < 8; ++cc) {   // B: 32KB
      const int off = w * 8192 + cc * 1024 + l * 16;
      const int row = off >> 7, colb = off & 127;
      const char* gB = (const char*)BT + ((size_t)(tn0 + row) * K + k0) * 2 + colb;
      gload_lds16(gB, (char*)Bs + w * 8192 + cc * 1024);
    }
    __syncthreads();
#pragma unroll
    for (int ks = 0; ks < 2; ++ks) {
      half8 a[4], b[8];
#pragma unroll
      for (int i = 0; i < 4; ++i)
        a[i] = *(const half8*)&As[(wr * 64 + i * 16 + c) * 64 + ks * 32 + g * 8];
#pragma unroll
      for (int j = 0; j < 8; ++j)
        b[j] = *(const half8*)&Bs[(wc * 128 + j * 16 + c) * 64 + ks * 32 + g * 8];
#pragma unroll
      for (int i = 0; i < 4; ++i)
#pragma unroll
        for (int j = 0; j < 8; ++j) acc[i][j] = mfma16h(a[i], b[j], acc[i][j]);
    }
    __syncthreads();
  }

#pragma unroll
  for (int i = 0; i < 4; ++i) {
    const int row0 = tm0 + wr * 64 + i * 16 + g * 4;
#pragma unroll
    for (int j = 0; j < 8; ++j) {
      const int col = tn0 + wc * 128 + j * 16 + c;
      if constexpr (MODE == 0) {
        const float bv = bias[col];
#pragma unroll
        for (int r = 0; r < 4; ++r)
          ((_Float16*)Cout)[(size_t)(row0 + r) * N + col] =
              (_Float16)((acc[i][j][r] + bv) * cscale);
      } else if constexpr (MODE == 4) {
        const int bI = row0 >> 11;
        const int colk = col & 2047;
        const int hI = colk >> 7, dI = colk & 127;
        if (col < 2048) {       // K blocked [bh][nb][64nn][128d]
          const float bv = bias[colk];
#pragma unroll
          for (int r = 0; r < 4; ++r) {
            const int n = (row0 + r) & 2047;
            ((_Float16*)Cout)[(size_t)((bI * 16 + hI) * 32 + (n >> 6)) * 8192 +
                              (n & 63) * 128 + dI] = (_Float16)(acc[i][j][r] + bv);
          }
        } else {                // V blocked [bh][nb][128d][64nn]
          const float bv = bias2[colk];
          half4 pk;
#pragma unroll
          for (int r = 0; r < 4; ++r) pk[r] = (_Float16)(acc[i][j][r] + bv);
          const int nI = row0 & 2047;
          *(half4*)((_Float16*)Cout2 +
                    (size_t)((bI * 16 + hI) * 32 + (nI >> 6)) * 8192 + dI * 64 + (nI & 63)) = pk;
        }
      } else {                  // MODE 2: fp32 row-major
        const float bv = bias[col];
#pragma unroll
        for (int r = 0; r < 4; ++r)
          ((float*)Cout)[(size_t)(row0 + r) * N + col] = acc[i][j][r] + bv;
      }
    }
  }
}

// ---------- flash attention: 16 heads, HD=128, N=2048, non-causal ----------
// r12 kernel VERBATIM (proven 100us): 4 waves x 32 q-rows, K+V LDS double-buffered,
// swapped-operand MFMA (P r-contiguous -> b64 P-stores), lane-local row sums,
// unnormalized base-2 softmax (q pre-scaled by scale*log2(e)).
__global__ __launch_bounds__(256, 2) void flash_attn(const _Float16* __restrict__ Q,
                                                     const _Float16* __restrict__ KB,
                                                     const _Float16* __restrict__ VB,
                                                     _Float16* __restrict__ O) {
  __shared__ _Float16 Ks[2][8192];   // 16KB/buf: [64 kv][128 d], 256B rows, XOR-swizzled
  __shared__ _Float16 Vs[2][8192];   // 16KB/buf: [128 d][64 kv], 128B rows, XOR-swizzled
  __shared__ _Float16 Ps[4][2048];   // 4KB/wave: [32 q][64 kv], XOR-swizzled
  const int tid = threadIdx.x, w = tid >> 6, l = tid & 63, g = l >> 4, c = l & 15;
  const int wgid = blockIdx.x + blockIdx.y * 16;
  const int xcd = wgid & 7, idx = wgid >> 3;
  const int bh = xcd * 4 + (idx >> 4), qblk = idx & 15;
  const int b = bh >> 4, h = bh & 15;
  const size_t rowQ0 = (size_t)b * 2048 + qblk * 128 + w * 32;
  const _Float16* kvK = KB + (size_t)bh * 262144;
  const _Float16* kvV = VB + (size_t)bh * 262144;
  const int sw = (c & 7) << 4;

  auto stageK = [&](int t, int buf) {
#pragma unroll
    for (int i = 0; i < 4; ++i) {
      const int o = i * 4096 + w * 1024 + l * 16;
      const int row = o >> 8;
      const int src = (o & ~255) | ((o & 255) ^ ((row & 7) << 4));
      gload_lds16((const char*)(kvK + t * 8192) + src,
                  (char*)&Ks[buf][0] + i * 4096 + w * 1024);
    }
  };
  auto stageV = [&](int t, int buf) {
#pragma unroll
    for (int i = 0; i < 4; ++i) {
      const int o = i * 4096 + w * 1024 + l * 16;
      const int row = o >> 7;
      const int src = (o & ~127) | ((o & 127) ^ ((row & 7) << 4));
      gload_lds16((const char*)(kvV + t * 8192) + src,
                  (char*)&Vs[buf][0] + i * 4096 + w * 1024);
    }
  };

  stageK(0, 0);
  stageV(0, 0);
  // Q as MFMA B-operand: lane (c,g) supplies Q[q=rowQ0+m*16+c][d=ks*32+g*8..+8]
  half8 bq[2][4];
#pragma unroll
  for (int m = 0; m < 2; ++m)
#pragma unroll
    for (int ks = 0; ks < 4; ++ks)
      bq[m][ks] = *(const half8*)&Q[(rowQ0 + m * 16 + c) * 2048 + h * 128 + ks * 32 + g * 8];

  f32x4 accO[2][8];   // O^T: accO[m][n8][r] = O[q=m*16+c][d=n8*16+g*4+r]
#pragma unroll
  for (int m = 0; m < 2; ++m)
#pragma unroll
    for (int n = 0; n < 8; ++n) accO[m][n] = f32x4{0.f, 0.f, 0.f, 0.f};
  float lsum[2] = {0.f, 0.f};   // row-sum partial for q = m*16+c (lane-local)

  __syncthreads();          // drains stage(0)

  for (int t = 0; t < 32; ++t) {
    const int cur = t & 1;
    if (t < 31) { stageK(t + 1, cur ^ 1); stageV(t + 1, cur ^ 1); }  // in flight all tile
    // --- swapped QK^T: T[kv][q] = mfma(A=K, B=Q) ---
    f32x4 accS[2][4];   // [m][kv16]: T[kv=kv16*16+g*4+r][q=m*16+c]
#pragma unroll
    for (int m = 0; m < 2; ++m)
#pragma unroll
      for (int n = 0; n < 4; ++n) accS[m][n] = f32x4{0.f, 0.f, 0.f, 0.f};
    __builtin_amdgcn_s_setprio(1);
#pragma unroll
    for (int ks = 0; ks < 4; ++ks) {
      half8 ak[4];
#pragma unroll
      for (int n = 0; n < 4; ++n) {
        const int row = n * 16 + c;
        ak[n] = *(const half8*)((const char*)&Ks[cur][0] + row * 256 +
                                ((ks * 64 + g * 16) ^ sw));
      }
#pragma unroll
      for (int m = 0; m < 2; ++m)
#pragma unroll
        for (int n = 0; n < 4; ++n) accS[m][n] = mfma16h(ak[n], bq[m][ks], accS[m][n]);
    }
    __builtin_amdgcn_s_setprio(0);
    // --- exp2 + pack pairs + b64 P-write to Ps[q][kv] (swizzled), lane-local lsum ---
#pragma unroll
    for (int m = 0; m < 2; ++m)
#pragma unroll
      for (int n = 0; n < 4; ++n) {
        const float p0 = exp2f(accS[m][n][0]);
        const float p1 = exp2f(accS[m][n][1]);
        const float p2 = exp2f(accS[m][n][2]);
        const float p3 = exp2f(accS[m][n][3]);
        lsum[m] += (p0 + p1) + (p2 + p3);
        fp16x2 lo = __builtin_amdgcn_cvt_pkrtz(p0, p1);
        fp16x2 hi = __builtin_amdgcn_cvt_pkrtz(p2, p3);
        uint2 u;
        u.x = __builtin_bit_cast(unsigned, lo);
        u.y = __builtin_bit_cast(unsigned, hi);
        *(uint2*)((char*)&Ps[w][0] + (m * 16 + c) * 128 +
                  ((n * 32 + g * 8) ^ sw)) = u;
      }
    // --- swapped PV: O^T = mfma(A=V, B=P) from Ps + Vs[cur] ---
    __builtin_amdgcn_s_setprio(1);
#pragma unroll
    for (int ks = 0; ks < 2; ++ks) {
      half8 bp[2];
#pragma unroll
      for (int m = 0; m < 2; ++m)
        bp[m] = *(const half8*)((const char*)&Ps[w][0] + (m * 16 + c) * 128 +
                                ((ks * 64 + g * 16) ^ sw));
#pragma unroll
      for (int n = 0; n < 8; ++n) {
        half8 av = *(const half8*)((const char*)&Vs[cur][0] + (n * 16 + c) * 128 +
                                   ((ks * 64 + g * 16) ^ sw));
#pragma unroll
        for (int m = 0; m < 2; ++m) accO[m][n] = mfma16h(av, bp[m], accO[m][n]);
      }
    }
    __builtin_amdgcn_s_setprio(0);
    __syncthreads();   // waves done with [cur]; also drains stage(t+1) DMA
  }

  // --- finalize: reduce lsum across g-groups (q=c lane-local), normalize, b64 store ---
#pragma unroll
  for (int m = 0; m < 2; ++m) {
    float ps = lsum[m];
    ps += __shfl_xor(ps, 16, 64);
    ps += __shfl_xor(ps, 32, 64);
    const float inv = 1.f / ps;
    const size_t qrow = rowQ0 + m * 16 + c;
#pragma unroll
    for (int n = 0; n < 8; ++n) {
      half4 pk;
#pragma unroll
      for (int r = 0; r < 4; ++r) pk[r] = (_Float16)(accO[m][n][r] * inv);
      *(half4*)&O[qrow * 2048 + h * 128 + n * 16 + g * 4] = pk;
    }
  }
}

#define SCALE_QK 0.08838834764831845f
#define LOG2E    1.4426950408889634f

// ---------- host ----------
extern "C" void kernel_launch(void* const* d_in, const int* in_sizes, int n_in,
                              void* d_out, int out_size, void* d_ws, size_t ws_size,
                              hipStream_t stream) {
  const float* x   = (const float*)d_in[0];
  const float* Wq  = (const float*)d_in[1];
  const float* bq  = (const float*)d_in[2];
  const float* Wkv = (const float*)d_in[3];
  const float* bkv = (const float*)d_in[4];
  const float* Wku = (const float*)d_in[5];
  const float* bku = (const float*)d_in[6];
  const float* Wvu = (const float*)d_in[7];
  const float* bvu = (const float*)d_in[8];
  const float* Wo  = (const float*)d_in[9];
  const float* bo  = (const float*)d_in[10];
  float* out = (float*)d_out;

  char* ws = (char*)d_ws;
  const size_t MB = 1ull << 20;
  _Float16* xh   = (_Float16*)(ws + 0 * MB);    // 16MB; dead after q/kv GEMMs
  _Float16* attn = (_Float16*)(ws + 0 * MB);    //   -> reused by flash output
  _Float16* xl   = (_Float16*)(ws + 16 * MB);   // 16MB; dead after kv GEMM
  _Float16* qb   = (_Float16*)(ws + 16 * MB);   //   -> reused for q (written after)
  _Float16* kb   = (_Float16*)(ws + 32 * MB);   // 16MB (blocked K)
  _Float16* vT   = (_Float16*)(ws + 48 * MB);   // 16MB (blocked V^T)
  _Float16* WqT  = (_Float16*)(ws + 64 * MB);   // 8MB
  _Float16* WoT  = (_Float16*)(ws + 72 * MB);   // 8MB
  float* kv      = (float*)(ws + 80 * MB);      // 8MB fp32
  _Float16* kvq  = (_Float16*)(ws + 88 * MB);   // 4MB
  _Float16* WkvTh = (_Float16*)(ws + 92 * MB);  // 2MB
  _Float16* WkvTl = (_Float16*)(ws + 94 * MB);  // 2MB
  _Float16* WkuT = (_Float16*)(ws + 96 * MB);   // 2MB  (contiguous with WvuT ->
  _Float16* WvuT = (_Float16*)(ws + 98 * MB);   // 2MB   4096x512 fused weight)
  float* amax    = (float*)(ws + 100 * MB);     // 2KB

  hipMemsetAsync(amax, 0, 512 * sizeof(float), stream);

  cvt_split<<<8192, 256, 0, stream>>>((const float4*)x, (half4*)xh, (half4*)xl, 2097152);
  transpose_f16<<<dim3(64, 64, 2), dim3(32, 8), 0, stream>>>(Wq, Wo, WqT, nullptr, nullptr, 2048, 2048);
  transpose_f16<<<dim3(16, 64), dim3(32, 8), 0, stream>>>(Wkv, nullptr, WkvTh, WkvTl, nullptr, 2048, 512);
  // kv_latent: 128x64 tiles, grid (8,32)=256 blocks
  gemm_kv16<<<dim3(8, 32), 256, 0, stream>>>(xh, xl, WkvTh, WkvTl, bkv, kv, amax, 4096, 512, 2048);
  quant_kernel<<<2048, 256, 0, stream>>>((const float4*)kv, amax, (half4*)kvq, 524288);
  transpose_f16<<<dim3(64, 16, 2), dim3(32, 8), 0, stream>>>(Wku, Wvu, WkuT, nullptr, amax, 512, 2048);
  // q = (x @ Wq + bq) * scale*log2(e)  -> flash uses exp2 directly.  128x256 tiles.
  gemm_bt<0><<<dim3(8, 32), 256, 0, stream>>>(xh, WqT, qb, nullptr, bq, nullptr,
                                              SCALE_QK * LOG2E, 4096, 2048, 2048);
  gemm_bt<4><<<dim3(16, 32), 256, 0, stream>>>(kvq, WkuT, kb, vT, bku, bvu, 1.0f,
                                               4096, 4096, 512);
  flash_attn<<<dim3(16, 32), 256, 0, stream>>>(qb, kb, vT, attn);
  gemm_bt<2><<<dim3(8, 32), 256, 0, stream>>>(attn, WoT, out, nullptr, bo, nullptr, 1.0f,
                                              4096, 2048, 2048);

  (void)in_sizes; (void)n_in; (void)out_size; (void)ws_size;
}

// Round 16
// 318.457 us; speedup vs baseline: 1.1545x; 1.1545x over previous
//
#include <hip/hip_runtime.h>
#include <stdint.h>

// ---------- types ----------
typedef __attribute__((ext_vector_type(8))) _Float16 half8;  // MFMA A/B frag (4 VGPR)
typedef __attribute__((ext_vector_type(4))) _Float16 half4;  // 8B store
typedef __attribute__((ext_vector_type(2))) __fp16 fp16x2;   // cvt_pkrtz result type
typedef __attribute__((ext_vector_type(4))) float f32x4;     // MFMA C/D frag

#define AS1 __attribute__((address_space(1)))
#define AS3 __attribute__((address_space(3)))

__device__ inline void gload_lds16(const void* g, void* l) {
  __builtin_amdgcn_global_load_lds((const AS1 void*)g, (AS3 void*)l, 16, 0, 0);
}
__device__ inline f32x4 mfma16h(half8 a, half8 b, f32x4 c) {
  return __builtin_amdgcn_mfma_f32_16x16x32_f16(a, b, c, 0, 0, 0);
}

// ---------- x fp32 -> fp16 hi + fp16 lo*4096 (exact residual split) ----------
__global__ __launch_bounds__(256) void cvt_split(const float4* __restrict__ in,
                                                 half4* __restrict__ xh,
                                                 half4* __restrict__ xl, int nq) {
  int i = blockIdx.x * 256 + threadIdx.x;
  if (i >= nq) return;
  float4 v = in[i];
  float vv[4] = {v.x, v.y, v.z, v.w};
  half4 h, lo;
#pragma unroll
  for (int j = 0; j < 4; ++j) {
    _Float16 hh = (_Float16)vv[j];
    h[j] = hh;
    lo[j] = (_Float16)((vv[j] - (float)hh) * 4096.0f);
  }
  xh[i] = h;
  xl[i] = lo;
}

// ---------- transpose fp32 RxC -> fp16 CxR (+opt lo split, +opt row scale, +z-pair) ----------
__global__ __launch_bounds__(256) void transpose_f16(const float* __restrict__ in,
                                                     const float* __restrict__ in2,
                                                     _Float16* __restrict__ outh,
                                                     _Float16* __restrict__ outl,
                                                     const float* __restrict__ rowamax,
                                                     int R, int C) {
  __shared__ float t[32][33];
  if (blockIdx.z) { in = in2; outh += (size_t)R * C; }
  const int tx = threadIdx.x, ty = threadIdx.y;
  const int r0 = blockIdx.y * 32, c0 = blockIdx.x * 32;
#pragma unroll
  for (int k = 0; k < 4; ++k) {
    const int r = r0 + ty + k * 8;
    float s = 1.0f;
    if (rowamax) s = fmaxf(rowamax[r], 1e-5f) / 7.0f;   // same expr as quant kernel
    t[ty + k * 8][tx] = in[(size_t)r * C + c0 + tx] * s;
  }
  __syncthreads();
#pragma unroll
  for (int k = 0; k < 4; ++k) {
    const int c = c0 + ty + k * 8;
    float v = t[tx][ty + k * 8];
    _Float16 h = (_Float16)v;
    outh[(size_t)c * R + r0 + tx] = h;
    if (outl) outl[(size_t)c * R + r0 + tx] = (_Float16)((v - (float)h) * 4096.0f);
  }
}

// ---------- kv_latent GEMM via fp16 hi/lo 3-term MFMA (fp32-equivalent) ----------
// 64x64 tile, grid (8,64)=512 blocks -> 2 blocks/CU (r10-proven optimum).
__global__ __launch_bounds__(256) void gemm_kv16(const _Float16* __restrict__ Ah,
                                                 const _Float16* __restrict__ Al,
                                                 const _Float16* __restrict__ Bh,
                                                 const _Float16* __restrict__ Bl,
                                                 const float* __restrict__ bias,
                                                 float* __restrict__ C,
                                                 float* __restrict__ amax,
                                                 int M, int N, int K) {
  __shared__ _Float16 sAh[64 * 64], sAl[64 * 64];
  __shared__ _Float16 sBh[64 * 64], sBl[64 * 64];
  const int tid = threadIdx.x;
  const int w = tid >> 6, l = tid & 63, g = l >> 4, c = l & 15;
  const int wr = w >> 1, wc = w & 1;                 // wave tile 32x32
  int wgid = blockIdx.x + blockIdx.y * gridDim.x;
  const int nwg = gridDim.x * gridDim.y;
  wgid = (wgid & 7) * (nwg >> 3) + (wgid >> 3);
  const int tm0 = (wgid / gridDim.x) * 64, n0 = (wgid % gridDim.x) * 64;

  f32x4 acc[2][2], acc2[2][2];
#pragma unroll
  for (int i = 0; i < 2; ++i)
#pragma unroll
    for (int j = 0; j < 2; ++j) {
      acc[i][j] = f32x4{0.f, 0.f, 0.f, 0.f};
      acc2[i][j] = f32x4{0.f, 0.f, 0.f, 0.f};
    }

  for (int k0 = 0; k0 < K; k0 += 64) {
#pragma unroll
    for (int cc = 0; cc < 2; ++cc) {                 // A hi/lo: 8KB each
      const int off = w * 2048 + cc * 1024 + l * 16;
      const int row = off >> 7, colb = off & 127;
      const char* gA = (const char*)Ah + ((size_t)(tm0 + row) * K + k0) * 2 + colb;
      const char* gL = (const char*)Al + ((size_t)(tm0 + row) * K + k0) * 2 + colb;
      gload_lds16(gA, (char*)sAh + w * 2048 + cc * 1024);
      gload_lds16(gL, (char*)sAl + w * 2048 + cc * 1024);
    }
#pragma unroll
    for (int cc = 0; cc < 2; ++cc) {                 // B hi/lo: 8KB each
      const int off = w * 2048 + cc * 1024 + l * 16;
      const int row = off >> 7, colb = off & 127;
      const char* gB = (const char*)Bh + ((size_t)(n0 + row) * K + k0) * 2 + colb;
      const char* gL = (const char*)Bl + ((size_t)(n0 + row) * K + k0) * 2 + colb;
      gload_lds16(gB, (char*)sBh + w * 2048 + cc * 1024);
      gload_lds16(gL, (char*)sBl + w * 2048 + cc * 1024);
    }
    __syncthreads();
#pragma unroll
    for (int ks = 0; ks < 2; ++ks) {
      half8 ah[2], al[2], bh[2], bl[2];
#pragma unroll
      for (int i = 0; i < 2; ++i) {
        ah[i] = *(const half8*)&sAh[(wr * 32 + i * 16 + c) * 64 + ks * 32 + g * 8];
        al[i] = *(const half8*)&sAl[(wr * 32 + i * 16 + c) * 64 + ks * 32 + g * 8];
      }
#pragma unroll
      for (int j = 0; j < 2; ++j) {
        bh[j] = *(const half8*)&sBh[(wc * 32 + j * 16 + c) * 64 + ks * 32 + g * 8];
        bl[j] = *(const half8*)&sBl[(wc * 32 + j * 16 + c) * 64 + ks * 32 + g * 8];
      }
#pragma unroll
      for (int i = 0; i < 2; ++i)
#pragma unroll
        for (int j = 0; j < 2; ++j) {
          acc[i][j] = mfma16h(ah[i], bh[j], acc[i][j]);
          acc2[i][j] = mfma16h(al[i], bh[j], acc2[i][j]);
          acc2[i][j] = mfma16h(ah[i], bl[j], acc2[i][j]);
        }
    }
    __syncthreads();
  }

  float cm[2] = {0.f, 0.f};
#pragma unroll
  for (int i = 0; i < 2; ++i) {
    const int row0 = tm0 + wr * 32 + i * 16 + g * 4;
#pragma unroll
    for (int j = 0; j < 2; ++j) {
      const int col = n0 + wc * 32 + j * 16 + c;
      const float bv = bias[col];
#pragma unroll
      for (int r = 0; r < 4; ++r) {
        float v = acc[i][j][r] + acc2[i][j][r] * 2.44140625e-4f + bv;  // 2^-12 exact
        C[(size_t)(row0 + r) * N + col] = v;
        cm[j] = fmaxf(cm[j], fabsf(v));
      }
    }
  }
#pragma unroll
  for (int j = 0; j < 2; ++j) {
    float m = cm[j];
    m = fmaxf(m, __shfl_xor(m, 16, 64));
    m = fmaxf(m, __shfl_xor(m, 32, 64));
    if (g == 0) atomicMax((int*)amax + (n0 + wc * 32 + j * 16 + c), __float_as_int(m));
  }
}

// ---------- int4 quant: store INTEGER q (-8..7) as fp16 (exact) ----------
__global__ __launch_bounds__(256) void quant_kernel(const float4* __restrict__ kv,
                                                    const float* __restrict__ amax,
                                                    half4* __restrict__ kvq, int nq) {
  int i = blockIdx.x * 256 + threadIdx.x;
  if (i >= nq) return;
  float4 v = kv[i];
  int r0 = (i * 4) & 511;
  half4 o;
#pragma unroll
  for (int j = 0; j < 4; ++j) {
    float s = fmaxf(amax[r0 + j], 1e-5f) / 7.0f;
    float val = (j == 0) ? v.x : (j == 1) ? v.y : (j == 2) ? v.z : v.w;
    float q = rintf(val / s);                         // round-half-even == jnp.round
    q = fminf(7.f, fmaxf(-8.f, q));
    o[j] = (_Float16)q;                               // small ints exact
  }
  kvq[i] = o;
}

// ---------- fp16 MFMA GEMM: C = A @ BT^T + bias.  A: MxK, BT: NxK ----------
// 128x128 tile (r12-proven optimum). MODE 0: f16 row-major (×cscale); MODE 2: fp32;
// MODE 4: fused k/v up-proj (cols<2048 -> K blocked; cols>=2048 -> V blocked).
template <int MODE>
__global__ __launch_bounds__(256) void gemm_bt(const _Float16* __restrict__ A,
                                               const _Float16* __restrict__ BT,
                                               void* __restrict__ Cout,
                                               void* __restrict__ Cout2,
                                               const float* __restrict__ bias,
                                               const float* __restrict__ bias2,
                                               float cscale,
                                               int M, int N, int K) {
  __shared__ _Float16 As[128 * 64];
  __shared__ _Float16 Bs[128 * 64];
  const int tid = threadIdx.x;
  const int w = tid >> 6, l = tid & 63, g = l >> 4, c = l & 15;
  const int wr = w >> 1, wc = w & 1;
  int wgid = blockIdx.x + blockIdx.y * gridDim.x;
  const int nwg = gridDim.x * gridDim.y;
  wgid = (wgid & 7) * (nwg >> 3) + (wgid >> 3);
  const int tm0 = (wgid / gridDim.x) * 128, tn0 = (wgid % gridDim.x) * 128;

  f32x4 acc[4][4];
#pragma unroll
  for (int i = 0; i < 4; ++i)
#pragma unroll
    for (int j = 0; j < 4; ++j) acc[i][j] = f32x4{0.f, 0.f, 0.f, 0.f};

  for (int k0 = 0; k0 < K; k0 += 64) {
#pragma unroll
    for (int cc = 0; cc < 4; ++cc) {
      const int off = w * 4096 + cc * 1024 + l * 16;
      const int row = off >> 7, colb = off & 127;
      const char* gA = (const char*)A + ((size_t)(tm0 + row) * K + k0) * 2 + colb;
      const char* gB = (const char*)BT + ((size_t)(tn0 + row) * K + k0) * 2 + colb;
      gload_lds16(gA, (char*)As + w * 4096 + cc * 1024);
      gload_lds16(gB, (char*)Bs + w * 4096 + cc * 1024);
    }
    __syncthreads();
#pragma unroll
    for (int ks = 0; ks < 2; ++ks) {
      half8 a[4], b[4];
#pragma unroll
      for (int i = 0; i < 4; ++i)
        a[i] = *(const half8*)&As[(wr * 64 + i * 16 + c) * 64 + ks * 32 + g * 8];
#pragma unroll
      for (int j = 0; j < 4; ++j)
        b[j] = *(const half8*)&Bs[(wc * 64 + j * 16 + c) * 64 + ks * 32 + g * 8];
#pragma unroll
      for (int i = 0; i < 4; ++i)
#pragma unroll
        for (int j = 0; j < 4; ++j) acc[i][j] = mfma16h(a[i], b[j], acc[i][j]);
    }
    __syncthreads();
  }

#pragma unroll
  for (int i = 0; i < 4; ++i) {
    const int row0 = tm0 + wr * 64 + i * 16 + g * 4;
#pragma unroll
    for (int j = 0; j < 4; ++j) {
      const int col = tn0 + wc * 64 + j * 16 + c;
      if constexpr (MODE == 0) {
        const float bv = bias[col];
#pragma unroll
        for (int r = 0; r < 4; ++r)
          ((_Float16*)Cout)[(size_t)(row0 + r) * N + col] =
              (_Float16)((acc[i][j][r] + bv) * cscale);
      } else if constexpr (MODE == 4) {
        const int bI = row0 >> 11;
        const int colk = col & 2047;
        const int hI = colk >> 7, dI = colk & 127;
        if (col < 2048) {       // K blocked [bh][nb][64nn][128d]
          const float bv = bias[colk];
#pragma unroll
          for (int r = 0; r < 4; ++r) {
            const int n = (row0 + r) & 2047;
            ((_Float16*)Cout)[(size_t)((bI * 16 + hI) * 32 + (n >> 6)) * 8192 +
                              (n & 63) * 128 + dI] = (_Float16)(acc[i][j][r] + bv);
          }
        } else {                // V blocked [bh][nb][128d][64nn]
          const float bv = bias2[colk];
          half4 pk;
#pragma unroll
          for (int r = 0; r < 4; ++r) pk[r] = (_Float16)(acc[i][j][r] + bv);
          const int nI = row0 & 2047;
          *(half4*)((_Float16*)Cout2 +
                    (size_t)((bI * 16 + hI) * 32 + (nI >> 6)) * 8192 + dI * 64 + (nI & 63)) = pk;
        }
      } else {                  // MODE 2: fp32 row-major
        const float bv = bias[col];
#pragma unroll
        for (int r = 0; r < 4; ++r)
          ((float*)Cout)[(size_t)(row0 + r) * N + col] = acc[i][j][r] + bv;
      }
    }
  }
}

// ---------- flash attention: 16 heads, HD=128, N=2048, non-causal ----------
// r12 kernel VERBATIM (proven 100us): 4 waves x 32 q-rows, K+V LDS double-buffered,
// swapped-operand MFMA (P r-contiguous -> b64 P-stores), lane-local row sums,
// unnormalized base-2 softmax (q pre-scaled by scale*log2(e)).
__global__ __launch_bounds__(256, 2) void flash_attn(const _Float16* __restrict__ Q,
                                                     const _Float16* __restrict__ KB,
                                                     const _Float16* __restrict__ VB,
                                                     _Float16* __restrict__ O) {
  __shared__ _Float16 Ks[2][8192];   // 16KB/buf: [64 kv][128 d], 256B rows, XOR-swizzled
  __shared__ _Float16 Vs[2][8192];   // 16KB/buf: [128 d][64 kv], 128B rows, XOR-swizzled
  __shared__ _Float16 Ps[4][2048];   // 4KB/wave: [32 q][64 kv], XOR-swizzled
  const int tid = threadIdx.x, w = tid >> 6, l = tid & 63, g = l >> 4, c = l & 15;
  const int wgid = blockIdx.x + blockIdx.y * 16;
  const int xcd = wgid & 7, idx = wgid >> 3;
  const int bh = xcd * 4 + (idx >> 4), qblk = idx & 15;
  const int b = bh >> 4, h = bh & 15;
  const size_t rowQ0 = (size_t)b * 2048 + qblk * 128 + w * 32;
  const _Float16* kvK = KB + (size_t)bh * 262144;
  const _Float16* kvV = VB + (size_t)bh * 262144;
  const int sw = (c & 7) << 4;

  auto stageK = [&](int t, int buf) {
#pragma unroll
    for (int i = 0; i < 4; ++i) {
      const int o = i * 4096 + w * 1024 + l * 16;
      const int row = o >> 8;
      const int src = (o & ~255) | ((o & 255) ^ ((row & 7) << 4));
      gload_lds16((const char*)(kvK + t * 8192) + src,
                  (char*)&Ks[buf][0] + i * 4096 + w * 1024);
    }
  };
  auto stageV = [&](int t, int buf) {
#pragma unroll
    for (int i = 0; i < 4; ++i) {
      const int o = i * 4096 + w * 1024 + l * 16;
      const int row = o >> 7;
      const int src = (o & ~127) | ((o & 127) ^ ((row & 7) << 4));
      gload_lds16((const char*)(kvV + t * 8192) + src,
                  (char*)&Vs[buf][0] + i * 4096 + w * 1024);
    }
  };

  stageK(0, 0);
  stageV(0, 0);
  // Q as MFMA B-operand: lane (c,g) supplies Q[q=rowQ0+m*16+c][d=ks*32+g*8..+8]
  half8 bq[2][4];
#pragma unroll
  for (int m = 0; m < 2; ++m)
#pragma unroll
    for (int ks = 0; ks < 4; ++ks)
      bq[m][ks] = *(const half8*)&Q[(rowQ0 + m * 16 + c) * 2048 + h * 128 + ks * 32 + g * 8];

  f32x4 accO[2][8];   // O^T: accO[m][n8][r] = O[q=m*16+c][d=n8*16+g*4+r]
#pragma unroll
  for (int m = 0; m < 2; ++m)
#pragma unroll
    for (int n = 0; n < 8; ++n) accO[m][n] = f32x4{0.f, 0.f, 0.f, 0.f};
  float lsum[2] = {0.f, 0.f};   // row-sum partial for q = m*16+c (lane-local)

  __syncthreads();          // drains stage(0)

  for (int t = 0; t < 32; ++t) {
    const int cur = t & 1;
    if (t < 31) { stageK(t + 1, cur ^ 1); stageV(t + 1, cur ^ 1); }  // in flight all tile
    // --- swapped QK^T: T[kv][q] = mfma(A=K, B=Q) ---
    f32x4 accS[2][4];   // [m][kv16]: T[kv=kv16*16+g*4+r][q=m*16+c]
#pragma unroll
    for (int m = 0; m < 2; ++m)
#pragma unroll
      for (int n = 0; n < 4; ++n) accS[m][n] = f32x4{0.f, 0.f, 0.f, 0.f};
    __builtin_amdgcn_s_setprio(1);
#pragma unroll
    for (int ks = 0; ks < 4; ++ks) {
      half8 ak[4];
#pragma unroll
      for (int n = 0; n < 4; ++n) {
        const int row = n * 16 + c;
        ak[n] = *(const half8*)((const char*)&Ks[cur][0] + row * 256 +
                                ((ks * 64 + g * 16) ^ sw));
      }
#pragma unroll
      for (int m = 0; m < 2; ++m)
#pragma unroll
        for (int n = 0; n < 4; ++n) accS[m][n] = mfma16h(ak[n], bq[m][ks], accS[m][n]);
    }
    __builtin_amdgcn_s_setprio(0);
    // --- exp2 + pack pairs + b64 P-write to Ps[q][kv] (swizzled), lane-local lsum ---
#pragma unroll
    for (int m = 0; m < 2; ++m)
#pragma unroll
      for (int n = 0; n < 4; ++n) {
        const float p0 = exp2f(accS[m][n][0]);
        const float p1 = exp2f(accS[m][n][1]);
        const float p2 = exp2f(accS[m][n][2]);
        const float p3 = exp2f(accS[m][n][3]);
        lsum[m] += (p0 + p1) + (p2 + p3);
        fp16x2 lo = __builtin_amdgcn_cvt_pkrtz(p0, p1);
        fp16x2 hi = __builtin_amdgcn_cvt_pkrtz(p2, p3);
        uint2 u;
        u.x = __builtin_bit_cast(unsigned, lo);
        u.y = __builtin_bit_cast(unsigned, hi);
        *(uint2*)((char*)&Ps[w][0] + (m * 16 + c) * 128 +
                  ((n * 32 + g * 8) ^ sw)) = u;
      }
    // --- swapped PV: O^T = mfma(A=V, B=P) from Ps + Vs[cur] ---
    __builtin_amdgcn_s_setprio(1);
#pragma unroll
    for (int ks = 0; ks < 2; ++ks) {
      half8 bp[2];
#pragma unroll
      for (int m = 0; m < 2; ++m)
        bp[m] = *(const half8*)((const char*)&Ps[w][0] + (m * 16 + c) * 128 +
                                ((ks * 64 + g * 16) ^ sw));
#pragma unroll
      for (int n = 0; n < 8; ++n) {
        half8 av = *(const half8*)((const char*)&Vs[cur][0] + (n * 16 + c) * 128 +
                                   ((ks * 64 + g * 16) ^ sw));
#pragma unroll
        for (int m = 0; m < 2; ++m) accO[m][n] = mfma16h(av, bp[m], accO[m][n]);
      }
    }
    __builtin_amdgcn_s_setprio(0);
    __syncthreads();   // waves done with [cur]; also drains stage(t+1) DMA
  }

  // --- finalize: reduce lsum across g-groups (q=c lane-local), normalize, b64 store ---
#pragma unroll
  for (int m = 0; m < 2; ++m) {
    float ps = lsum[m];
    ps += __shfl_xor(ps, 16, 64);
    ps += __shfl_xor(ps, 32, 64);
    const float inv = 1.f / ps;
    const size_t qrow = rowQ0 + m * 16 + c;
#pragma unroll
    for (int n = 0; n < 8; ++n) {
      half4 pk;
#pragma unroll
      for (int r = 0; r < 4; ++r) pk[r] = (_Float16)(accO[m][n][r] * inv);
      *(half4*)&O[qrow * 2048 + h * 128 + n * 16 + g * 4] = pk;
    }
  }
}

#define SCALE_QK 0.08838834764831845f
#define LOG2E    1.4426950408889634f

// ---------- host ----------
extern "C" void kernel_launch(void* const* d_in, const int* in_sizes, int n_in,
                              void* d_out, int out_size, void* d_ws, size_t ws_size,
                              hipStream_t stream) {
  const float* x   = (const float*)d_in[0];
  const float* Wq  = (const float*)d_in[1];
  const float* bq  = (const float*)d_in[2];
  const float* Wkv = (const float*)d_in[3];
  const float* bkv = (const float*)d_in[4];
  const float* Wku = (const float*)d_in[5];
  const float* bku = (const float*)d_in[6];
  const float* Wvu = (const float*)d_in[7];
  const float* bvu = (const float*)d_in[8];
  const float* Wo  = (const float*)d_in[9];
  const float* bo  = (const float*)d_in[10];
  float* out = (float*)d_out;

  char* ws = (char*)d_ws;
  const size_t MB = 1ull << 20;
  _Float16* xh   = (_Float16*)(ws + 0 * MB);    // 16MB; dead after q/kv GEMMs
  _Float16* attn = (_Float16*)(ws + 0 * MB);    //   -> reused by flash output
  _Float16* xl   = (_Float16*)(ws + 16 * MB);   // 16MB; dead after kv GEMM
  _Float16* qb   = (_Float16*)(ws + 16 * MB);   //   -> reused for q (written after)
  _Float16* kb   = (_Float16*)(ws + 32 * MB);   // 16MB (blocked K)
  _Float16* vT   = (_Float16*)(ws + 48 * MB);   // 16MB (blocked V^T)
  _Float16* WqT  = (_Float16*)(ws + 64 * MB);   // 8MB
  _Float16* WoT  = (_Float16*)(ws + 72 * MB);   // 8MB
  float* kv      = (float*)(ws + 80 * MB);      // 8MB fp32
  _Float16* kvq  = (_Float16*)(ws + 88 * MB);   // 4MB
  _Float16* WkvTh = (_Float16*)(ws + 92 * MB);  // 2MB
  _Float16* WkvTl = (_Float16*)(ws + 94 * MB);  // 2MB
  _Float16* WkuT = (_Float16*)(ws + 96 * MB);   // 2MB  (contiguous with WvuT ->
  _Float16* WvuT = (_Float16*)(ws + 98 * MB);   // 2MB   4096x512 fused weight)
  float* amax    = (float*)(ws + 100 * MB);     // 2KB

  hipMemsetAsync(amax, 0, 512 * sizeof(float), stream);

  cvt_split<<<8192, 256, 0, stream>>>((const float4*)x, (half4*)xh, (half4*)xl, 2097152);
  transpose_f16<<<dim3(64, 64, 2), dim3(32, 8), 0, stream>>>(Wq, Wo, WqT, nullptr, nullptr, 2048, 2048);
  transpose_f16<<<dim3(16, 64), dim3(32, 8), 0, stream>>>(Wkv, nullptr, WkvTh, WkvTl, nullptr, 2048, 512);
  gemm_kv16<<<dim3(8, 64), 256, 0, stream>>>(xh, xl, WkvTh, WkvTl, bkv, kv, amax, 4096, 512, 2048);
  quant_kernel<<<2048, 256, 0, stream>>>((const float4*)kv, amax, (half4*)kvq, 524288);
  transpose_f16<<<dim3(64, 16, 2), dim3(32, 8), 0, stream>>>(Wku, Wvu, WkuT, nullptr, amax, 512, 2048);
  // q = (x @ Wq + bq) * scale*log2(e)  -> flash uses exp2 directly
  gemm_bt<0><<<dim3(16, 32), 256, 0, stream>>>(xh, WqT, qb, nullptr, bq, nullptr,
                                               SCALE_QK * LOG2E, 4096, 2048, 2048);
  gemm_bt<4><<<dim3(32, 32), 256, 0, stream>>>(kvq, WkuT, kb, vT, bku, bvu, 1.0f,
                                               4096, 4096, 512);
  flash_attn<<<dim3(16, 32), 256, 0, stream>>>(qb, kb, vT, attn);
  gemm_bt<2><<<dim3(16, 32), 256, 0, stream>>>(attn, WoT, out, nullptr, bo, nullptr, 1.0f,
                                               4096, 2048, 2048);

  (void)in_sizes; (void)n_in; (void)out_size; (void)ws_size;
}